// Round 8
// baseline (335.513 us; speedup 1.0000x reference)
//
#include <hip/hip_runtime.h>
#include <math.h>

typedef __attribute__((ext_vector_type(8))) short short8;  // 8 bf16
typedef __attribute__((ext_vector_type(4))) float f32x4;   // MFMA C/D

#define NB 32
#define CDIM 256
#define HW 1024
#define NROWS 32768
#define KCODES 1024
#define ZELEMS 8388608

#define OUT_ZQ_OFF 0
#define OUT_IDX_OFF 8388608
#define OUT_LOSS_OFF 8421376
#define OUT_PERP_OFF 8421377

// Workspace layout (bytes)
#define WS_CNT_OFF 0          // uint counts[1024]       (4 KB)
#define WS_E2D_OFF 4096       // double e2d[1024]        (8 KB)
#define WS_E2F_OFF 12288      // float e2f[1024]         (4 KB)
#define WS_LOSS_OFF 16384     // double loss_sum
#define WS_BT_OFF 32768       // bf16 B tiled [64][32][16][8] (512 KB)

#define BRN 32                // rows per argmin block
#define PAIR_MAX 256

__device__ inline ushort f2bf(float f) {  // fp32 -> bf16 bits, RNE
    unsigned u = __float_as_uint(f);
    unsigned r = (u + 0x7FFFu + ((u >> 16) & 1u)) >> 16;
    return (ushort)r;
}

// Per code k: e2 (double+float), bf16-hi row into tiled layout
// bt[ct=k>>4][slot=c>>3][kc=k&15][e=c&7]. Also zeroes counts/loss.
__global__ __launch_bounds__(64) void e2split_kernel(const float* __restrict__ embed,
                                                     double* __restrict__ e2d,
                                                     float* __restrict__ e2f,
                                                     ushort* __restrict__ bt,
                                                     unsigned* __restrict__ counts,
                                                     double* __restrict__ loss_sum) {
    int k = blockIdx.x, t = threadIdx.x;
    if (t == 0) counts[k] = 0u;
    if (k == 0 && t == 1) loss_sum[0] = 0.0;
    float4 v = *(const float4*)&embed[(size_t)k * CDIM + 4 * t];
    double s = (double)v.x * v.x + (double)v.y * v.y + (double)v.z * v.z + (double)v.w * v.w;
    #pragma unroll
    for (int off = 32; off; off >>= 1) s += __shfl_down(s, off);
    if (t == 0) { e2d[k] = s; e2f[k] = (float)s; }
    ushort h[4] = {f2bf(v.x), f2bf(v.y), f2bf(v.z), f2bf(v.w)};
    uint2 hh;
    hh.x = (unsigned)h[0] | ((unsigned)h[1] << 16);
    hh.y = (unsigned)h[2] | ((unsigned)h[3] << 16);
    // granule g = t>>1 (8 bf16 per granule); this thread covers half of it
    size_t off16 = (((size_t)(k >> 4) * 32 + (t >> 1)) * 16 + (k & 15)) * 8 + (t & 1) * 4;
    *(uint2*)&bt[off16] = hh;
}

// Fused: bf16-hi MFMA screening + parallel exact refine + gather/loss/counts.
// 512 thr (8 waves; wave w owns codes w*128..+127), 32 rows per block.
__global__ __launch_bounds__(512, 6) void argmin_fused_kernel(
        const float* __restrict__ z_e, const float* __restrict__ embed,
        const ushort* __restrict__ bt, const float* __restrict__ e2f,
        const double* __restrict__ e2d,
        float* __restrict__ out_zq, float* __restrict__ out_idx,
        unsigned* __restrict__ counts, double* __restrict__ loss_sum) {
    __shared__ ushort ahl[BRN * CDIM];          // bf16 x, swizzled (16 KB)
    __shared__ float e2s[KCODES];               // 4 KB
    __shared__ float mb1[8][BRN], mb2[8][BRN];
    __shared__ int mi1[8][BRN];
    __shared__ int besti[BRN];
    __shared__ float lims[BRN];                 // b1+tau2 for amb rows, else -1e30
    __shared__ float x2s[BRN];
    __shared__ float wmax[8];
    __shared__ float e2mx;
    __shared__ int pairs[PAIR_MAX];
    __shared__ double pd[PAIR_MAX];
    __shared__ int pair_cnt;
    __shared__ float xrow[CDIM];
    __shared__ double red_d[8];
    __shared__ int red_i[8];

    const int tid = threadIdx.x;
    const int w = tid >> 6, l = tid & 63;
    const int l15 = l & 15, l4 = l >> 4;
    const int n0 = blockIdx.x * BRN;
    const int bB = n0 >> 10;
    const int hw0 = n0 & (HW - 1);
    const size_t zbase = (size_t)bB * (CDIM * HW) + hw0;

    // ---- Stage e2 (+ wave-max for e2max) and x -> bf16 swizzled LDS ----
    float ve0 = e2f[tid], ve1 = e2f[512 + tid];
    e2s[tid] = ve0; e2s[512 + tid] = ve1;
    float m2 = fmaxf(ve0, ve1);
    #pragma unroll
    for (int off = 32; off; off >>= 1) m2 = fmaxf(m2, __shfl_xor(m2, off));
    if (l == 0) wmax[w] = m2;
    if (tid == 0) pair_cnt = 0;
    #pragma unroll
    for (int i = 0; i < 4; ++i) {
        int f4 = i * 512 + tid;
        int c = f4 >> 3, r4 = (f4 & 7) << 2;
        float4 v = *(const float4*)&z_e[zbase + (size_t)c * HW + r4];
        float vv[4] = {v.x, v.y, v.z, v.w};
        #pragma unroll
        for (int j = 0; j < 4; ++j) {
            int row = r4 + j;
            ahl[row * CDIM + ((((c >> 3) ^ (row & 7)) << 3) | (c & 7))] = f2bf(vv[j]);
        }
    }
    __syncthreads();

    // ---- per-row ||x||^2 (from bf16, inflated later) + e2max combine ----
    {
        int row = tid >> 4, g = tid & 15;
        const short8* a8 = (const short8*)&ahl[row * CDIM];
        short8 s0 = a8[g], s1 = a8[g + 16];
        float s = 0.f;
        #pragma unroll
        for (int e = 0; e < 8; ++e) {
            float f0 = __uint_as_float(((unsigned)(ushort)s0[e]) << 16);
            float f1 = __uint_as_float(((unsigned)(ushort)s1[e]) << 16);
            s = fmaf(f0, f0, s);
            s = fmaf(f1, f1, s);
        }
        #pragma unroll
        for (int off = 8; off; off >>= 1) s += __shfl_xor(s, off, 16);
        if (g == 0) x2s[row] = s;
        if (tid == 0) {
            float mm = wmax[0];
            #pragma unroll
            for (int ww = 1; ww < 8; ++ww) mm = fmaxf(mm, wmax[ww]);
            e2mx = mm;
        }
    }

    // ---- MFMA screening: d_hi = e2 - 2 (x_hi . e_hi) ----
    f32x4 acc[2][8];
    #pragma unroll
    for (int rt = 0; rt < 2; ++rt)
        #pragma unroll
        for (int ctl = 0; ctl < 8; ++ctl) acc[rt][ctl] = (f32x4){0.f, 0.f, 0.f, 0.f};

    const short8* B8 = (const short8*)bt;
    #pragma unroll 2
    for (int ks = 0; ks < 8; ++ks) {
        int asw = ((ks * 4 + l4) ^ (l15 & 7)) << 3;
        short8 ah0 = *(const short8*)&ahl[l15 * CDIM + asw];
        short8 ah1 = *(const short8*)&ahl[(16 + l15) * CDIM + asw];
        #pragma unroll
        for (int ctl = 0; ctl < 8; ++ctl) {
            short8 bh = B8[((w * 8 + ctl) * 32 + ks * 4 + l4) * 16 + l15];
            acc[0][ctl] = __builtin_amdgcn_mfma_f32_16x16x32_bf16(ah0, bh, acc[0][ctl], 0, 0, 0);
            acc[1][ctl] = __builtin_amdgcn_mfma_f32_16x16x32_bf16(ah1, bh, acc[1][ctl], 0, 0, 0);
        }
    }

    // ---- Fold to per-row top-2; lane holds row rt*16+l4*4+r, code w*128+ctl*16+l15 ----
    float tb1[8], tb2[8];
    int ti1[8];
    #pragma unroll
    for (int s = 0; s < 8; ++s) { tb1[s] = 1e30f; tb2[s] = 1e30f; ti1[s] = 0x7fffffff; }
    #pragma unroll
    for (int ctl = 0; ctl < 8; ++ctl) {
        int k = w * 128 + ctl * 16 + l15;
        float e2v = e2s[k];
        #pragma unroll
        for (int rt = 0; rt < 2; ++rt)
            #pragma unroll
            for (int r = 0; r < 4; ++r) {
                int s = rt * 4 + r;
                float d = fmaf(-2.f, acc[rt][ctl][r], e2v);
                bool lt = d < tb1[s];  // k ascends with ctl: strict < keeps smallest k
                tb2[s] = lt ? tb1[s] : fminf(tb2[s], d);
                if (lt) { tb1[s] = d; ti1[s] = k; }
            }
    }
    #pragma unroll
    for (int s = 0; s < 8; ++s) {
        #pragma unroll
        for (int off = 1; off < 16; off <<= 1) {
            float ob1 = __shfl_xor(tb1[s], off, 16);
            int oi1 = __shfl_xor(ti1[s], off, 16);
            float ob2 = __shfl_xor(tb2[s], off, 16);
            bool take = (ob1 < tb1[s]) || (ob1 == tb1[s] && oi1 < ti1[s]);
            float loser = take ? tb1[s] : ob1;
            if (take) { tb1[s] = ob1; ti1[s] = oi1; }
            tb2[s] = fminf(fminf(tb2[s], ob2), loser);
        }
    }
    if (l15 == 0) {
        #pragma unroll
        for (int rt = 0; rt < 2; ++rt)
            #pragma unroll
            for (int r = 0; r < 4; ++r) {
                int row = rt * 16 + l4 * 4 + r;
                mb1[w][row] = tb1[rt * 4 + r];
                mb2[w][row] = tb2[rt * 4 + r];
                mi1[w][row] = ti1[rt * 4 + r];
            }
    }
    __syncthreads();

    // ---- Merge 8 waves; rigorous hi-only bound -> ambiguity limit ----
    if (tid < BRN) {
        float B1 = 1e30f, B2 = 1e30f;
        int I1 = 0x7fffffff;
        #pragma unroll
        for (int ww = 0; ww < 8; ++ww) {
            float a1 = mb1[ww][tid], a2 = mb2[ww][tid];
            int ai = mi1[ww][tid];
            bool take = (a1 < B1) || (a1 == B1 && ai < I1);
            if (take) { B2 = fminf(B1, a2); B1 = a1; I1 = ai; }
            else      { B2 = fminf(B2, a1); }
        }
        besti[tid] = I1;
        float t2 = 2.f * (0.0079f * sqrtf(1.01f * x2s[tid] * e2mx) + 0.02f);
        lims[tid] = (B2 - B1 <= t2) ? (B1 + t2) : -1e30f;
    }
    __syncthreads();

    // ---- Pass A: parallel candidate collection from live acc registers ----
    #pragma unroll
    for (int rt = 0; rt < 2; ++rt)
        #pragma unroll
        for (int r = 0; r < 4; ++r) {
            int row = rt * 16 + l4 * 4 + r;
            float lim = lims[row];
            #pragma unroll
            for (int ctl = 0; ctl < 8; ++ctl) {
                int k = w * 128 + ctl * 16 + l15;
                float d = fmaf(-2.f, acc[rt][ctl][r], e2s[k]);
                if (d <= lim) {
                    int p = atomicAdd(&pair_cnt, 1);
                    if (p < PAIR_MAX) pairs[p] = (row << 10) | k;
                }
            }
        }
    __syncthreads();
    const int np = pair_cnt;

    if (np <= PAIR_MAX) {
        // ---- Pass B: one wave per pair, exact fp64 distance ----
        for (int pi = w; pi < np; pi += 8) {
            int pr = pairs[pi];
            int row = pr >> 10, k = pr & 1023;
            float4 e4 = *(const float4*)&embed[(size_t)k * CDIM + 4 * l];
            double dot = 0.0;
            #pragma unroll
            for (int j = 0; j < 4; ++j)
                dot = fma((double)(&e4.x)[j],
                          (double)z_e[zbase + (size_t)(4 * l + j) * HW + row], dot);
            #pragma unroll
            for (int off = 1; off < 64; off <<= 1) dot += __shfl_xor(dot, off);
            if (l == 0) pd[pi] = e2d[k] - 2.0 * dot;
        }
        __syncthreads();
        // ---- Pass C: per-row exact min over candidates ----
        if (tid < BRN) {
            double fb = 1e300;
            int fi = 0x7fffffff;
            bool any = false;
            for (int p = 0; p < np; ++p)
                if ((pairs[p] >> 10) == tid) {
                    double d = pd[p];
                    int k = pairs[p] & 1023;
                    if (d < fb || (d == fb && k < fi)) { fb = d; fi = k; }
                    any = true;
                }
            if (any) besti[tid] = fi;
        }
    } else {
        // ---- Overflow fallback (ultra-rare): serial full fp64 per amb row ----
        for (int row = 0; row < BRN; ++row) {
            if (lims[row] < -9e29f) continue;  // uniform branch (LDS)
            if (tid < CDIM) xrow[tid] = z_e[zbase + (size_t)tid * HW + row];
            __syncthreads();
            double bd = 1e300;
            int bi = 0x7fffffff;
            #pragma unroll
            for (int jj = 0; jj < 2; ++jj) {
                int k = jj * 512 + tid;
                const float* er = embed + (size_t)k * CDIM;
                double dot = 0.0;
                for (int c = 0; c < CDIM; ++c)
                    dot = fma((double)er[c], (double)xrow[c], dot);
                double d = e2d[k] - 2.0 * dot;
                if (d < bd || (d == bd && k < bi)) { bd = d; bi = k; }
            }
            #pragma unroll
            for (int off = 1; off < 64; off <<= 1) {
                double od = __shfl_xor(bd, off);
                int oi = __shfl_xor(bi, off);
                if (od < bd || (od == bd && oi < bi)) { bd = od; bi = oi; }
            }
            if (l == 0) { red_d[w] = bd; red_i[w] = bi; }
            __syncthreads();
            if (tid == 0) {
                double fb = red_d[0];
                int fi = red_i[0];
                #pragma unroll
                for (int ww = 1; ww < 8; ++ww)
                    if (red_d[ww] < fb || (red_d[ww] == fb && red_i[ww] < fi)) { fb = red_d[ww]; fi = red_i[ww]; }
                besti[row] = fi;
            }
            __syncthreads();
        }
    }
    __syncthreads();

    // ---- Fused epilogue: z_q_st, commitment-loss partial, idx, counts ----
    double lacc = 0.0;
    #pragma unroll
    for (int i = 0; i < 4; ++i) {
        int f4 = i * 512 + tid;
        int c = f4 >> 3, r4 = (f4 & 7) << 2;
        float4 x4 = *(const float4*)&z_e[zbase + (size_t)c * HW + r4];
        float o4[4];
        #pragma unroll
        for (int j = 0; j < 4; ++j) {
            int k = besti[r4 + j];
            float q = embed[(size_t)k * CDIM + c];
            float x = (&x4.x)[j];
            float r = q - x;            // z_q - z_e in fp32 (reference rounding)
            o4[j] = x + r;              // straight-through value
            lacc = fma((double)r, (double)r, lacc);
        }
        *(float4*)&out_zq[zbase + (size_t)c * HW + r4] = make_float4(o4[0], o4[1], o4[2], o4[3]);
    }
    if (tid < BRN) {
        int k = besti[tid];
        out_idx[n0 + tid] = (float)k;
        atomicAdd(&counts[k], 1u);
    }
    #pragma unroll
    for (int off = 32; off; off >>= 1) lacc += __shfl_down(lacc, off);
    if (l == 0) red_d[w] = lacc;
    __syncthreads();
    if (tid == 0) {
        double t = 0.0;
        #pragma unroll
        for (int ww = 0; ww < 8; ++ww) t += red_d[ww];
        atomicAdd(loss_sum, t);
    }
}

__global__ __launch_bounds__(256) void finalize_kernel(
        const unsigned* __restrict__ counts, const double* __restrict__ loss_sum,
        float* __restrict__ out) {
    int tid = threadIdx.x;
    float H = 0.f;
    for (int k = tid; k < KCODES; k += 256) {
        float p = (float)counts[k] / 32768.0f;
        H += p * logf(p + 1e-10f);
    }
    __shared__ float hr[4];
    #pragma unroll
    for (int off = 32; off; off >>= 1) H += __shfl_down(H, off);
    if ((tid & 63) == 0) hr[tid >> 6] = H;
    __syncthreads();
    if (tid == 0) {
        float Hs = hr[0] + hr[1] + hr[2] + hr[3];
        out[OUT_LOSS_OFF] = (float)(0.25 * (loss_sum[0] / (double)ZELEMS));
        out[OUT_PERP_OFF] = expf(-Hs);
    }
}

extern "C" void kernel_launch(void* const* d_in, const int* in_sizes, int n_in,
                              void* d_out, int out_size, void* d_ws, size_t ws_size,
                              hipStream_t stream) {
    const float* z_e = (const float*)d_in[0];
    const float* embed = (const float*)d_in[1];
    float* out = (float*)d_out;

    char* ws = (char*)d_ws;
    unsigned* ws_cnt = (unsigned*)(ws + WS_CNT_OFF);
    double* ws_e2d = (double*)(ws + WS_E2D_OFF);
    float* ws_e2f = (float*)(ws + WS_E2F_OFF);
    double* ws_loss = (double*)(ws + WS_LOSS_OFF);
    ushort* ws_bt = (ushort*)(ws + WS_BT_OFF);

    e2split_kernel<<<KCODES, 64, 0, stream>>>(embed, ws_e2d, ws_e2f, ws_bt, ws_cnt, ws_loss);
    argmin_fused_kernel<<<NROWS / BRN, 512, 0, stream>>>(z_e, embed, ws_bt, ws_e2f, ws_e2d,
                                                         out + OUT_ZQ_OFF, out + OUT_IDX_OFF,
                                                         ws_cnt, ws_loss);
    finalize_kernel<<<1, 256, 0, stream>>>(ws_cnt, ws_loss, out);
}

// Round 9
// 199.164 us; speedup vs baseline: 1.6846x; 1.6846x over previous
//
#include <hip/hip_runtime.h>
#include <math.h>

typedef __attribute__((ext_vector_type(8))) short short8;  // 8 bf16
typedef __attribute__((ext_vector_type(4))) float f32x4;   // MFMA C/D

#define NB 32
#define CDIM 256
#define HW 1024
#define NROWS 32768
#define KCODES 1024
#define ZELEMS 8388608

#define OUT_ZQ_OFF 0
#define OUT_IDX_OFF 8388608
#define OUT_LOSS_OFF 8421376
#define OUT_PERP_OFF 8421377

// Workspace layout (bytes)
#define WS_CNT_OFF 0          // uint counts[1024]       (4 KB)
#define WS_E2D_OFF 4096       // double e2d[1024]        (8 KB)
#define WS_E2F_OFF 12288      // float e2f[1024]         (4 KB)
#define WS_LOSS_OFF 16384     // double loss_sum
#define WS_BT_OFF 32768       // bf16 B tiled [64][32][16][8] (512 KB)

#define BRN 32                // rows per argmin block
#define PAIR_MAX 256
#define NWAVE 16

__device__ inline ushort f2bf(float f) {  // fp32 -> bf16 bits, RNE
    unsigned u = __float_as_uint(f);
    unsigned r = (u + 0x7FFFu + ((u >> 16) & 1u)) >> 16;
    return (ushort)r;
}

// Per code k: e2 (double+float), bf16-hi row into tiled layout
// bt[ct=k>>4][slot=c>>3][kc=k&15][e=c&7]. Also zeroes counts/loss.
__global__ __launch_bounds__(64) void e2split_kernel(const float* __restrict__ embed,
                                                     double* __restrict__ e2d,
                                                     float* __restrict__ e2f,
                                                     ushort* __restrict__ bt,
                                                     unsigned* __restrict__ counts,
                                                     double* __restrict__ loss_sum) {
    int k = blockIdx.x, t = threadIdx.x;
    if (t == 0) counts[k] = 0u;
    if (k == 0 && t == 1) loss_sum[0] = 0.0;
    float4 v = *(const float4*)&embed[(size_t)k * CDIM + 4 * t];
    double s = (double)v.x * v.x + (double)v.y * v.y + (double)v.z * v.z + (double)v.w * v.w;
    #pragma unroll
    for (int off = 32; off; off >>= 1) s += __shfl_down(s, off);
    if (t == 0) { e2d[k] = s; e2f[k] = (float)s; }
    ushort h[4] = {f2bf(v.x), f2bf(v.y), f2bf(v.z), f2bf(v.w)};
    uint2 hh;
    hh.x = (unsigned)h[0] | ((unsigned)h[1] << 16);
    hh.y = (unsigned)h[2] | ((unsigned)h[3] << 16);
    size_t off16 = (((size_t)(k >> 4) * 32 + (t >> 1)) * 16 + (k & 15)) * 8 + (t & 1) * 4;
    *(uint2*)&bt[off16] = hh;
}

// Fused: bf16-hi MFMA screening + parallel exact refine + gather/loss/counts.
// 1024 thr (16 waves; wave w owns codes w*64..+63), 32 rows per block.
// acc[2][4] = 32 VGPR -> fits 128-reg budget at 16 waves/CU (no spill).
__global__ __launch_bounds__(1024, 4) void argmin_fused_kernel(
        const float* __restrict__ z_e, const float* __restrict__ embed,
        const ushort* __restrict__ bt, const float* __restrict__ e2f,
        const double* __restrict__ e2d,
        float* __restrict__ out_zq, float* __restrict__ out_idx,
        unsigned* __restrict__ counts, double* __restrict__ loss_sum) {
    __shared__ ushort ahl[BRN * CDIM];          // bf16 x, swizzled (16 KB)
    __shared__ float e2s[KCODES];               // 4 KB
    __shared__ float mb1[NWAVE][BRN], mb2[NWAVE][BRN];
    __shared__ int mi1[NWAVE][BRN];
    __shared__ int besti[BRN];
    __shared__ float lims[BRN];                 // b1+tau2 for amb rows, else -1e30
    __shared__ float x2s[BRN];
    __shared__ float wmax[NWAVE];
    __shared__ float e2mx;
    __shared__ int pairs[PAIR_MAX];
    __shared__ double pd[PAIR_MAX];
    __shared__ int pair_cnt;
    __shared__ float xrow[CDIM];
    __shared__ double red_d[NWAVE];
    __shared__ int red_i[NWAVE];

    const int tid = threadIdx.x;
    const int w = tid >> 6, l = tid & 63;
    const int l15 = l & 15, l4 = l >> 4;
    const int n0 = blockIdx.x * BRN;
    const int bB = n0 >> 10;
    const int hw0 = n0 & (HW - 1);
    const size_t zbase = (size_t)bB * (CDIM * HW) + hw0;

    // ---- Stage e2 (+ wave-max) and x -> bf16 swizzled LDS ----
    float ve = e2f[tid];
    e2s[tid] = ve;
    float m2 = ve;
    #pragma unroll
    for (int off = 32; off; off >>= 1) m2 = fmaxf(m2, __shfl_xor(m2, off));
    if (l == 0) wmax[w] = m2;
    if (tid == 0) pair_cnt = 0;
    #pragma unroll
    for (int i = 0; i < 2; ++i) {
        int f4 = i * 1024 + tid;
        int c = f4 >> 3, r4 = (f4 & 7) << 2;
        float4 v = *(const float4*)&z_e[zbase + (size_t)c * HW + r4];
        float vv[4] = {v.x, v.y, v.z, v.w};
        #pragma unroll
        for (int j = 0; j < 4; ++j) {
            int row = r4 + j;
            ahl[row * CDIM + ((((c >> 3) ^ (row & 7)) << 3) | (c & 7))] = f2bf(vv[j]);
        }
    }
    __syncthreads();

    // ---- per-row ||x||^2 from bf16 (32 lanes per row) + e2max combine ----
    {
        int row = tid >> 5, g = tid & 31;
        const short8* a8 = (const short8*)&ahl[row * CDIM];
        short8 s0 = a8[g];
        float s = 0.f;
        #pragma unroll
        for (int e = 0; e < 8; ++e) {
            float f0 = __uint_as_float(((unsigned)(ushort)s0[e]) << 16);
            s = fmaf(f0, f0, s);
        }
        #pragma unroll
        for (int off = 16; off; off >>= 1) s += __shfl_xor(s, off, 32);
        if (g == 0) x2s[row] = s;
        if (tid == 0) {
            float mm = wmax[0];
            #pragma unroll
            for (int ww = 1; ww < NWAVE; ++ww) mm = fmaxf(mm, wmax[ww]);
            e2mx = mm;
        }
    }

    // ---- MFMA screening: d_hi = e2 - 2 (x_hi . e_hi); wave w: codes w*64..+63 ----
    f32x4 acc[2][4];
    #pragma unroll
    for (int rt = 0; rt < 2; ++rt)
        #pragma unroll
        for (int ctl = 0; ctl < 4; ++ctl) acc[rt][ctl] = (f32x4){0.f, 0.f, 0.f, 0.f};

    const short8* B8 = (const short8*)bt;
    #pragma unroll 2
    for (int ks = 0; ks < 8; ++ks) {
        int asw = ((ks * 4 + l4) ^ (l15 & 7)) << 3;
        short8 ah0 = *(const short8*)&ahl[l15 * CDIM + asw];
        short8 ah1 = *(const short8*)&ahl[(16 + l15) * CDIM + asw];
        #pragma unroll
        for (int ctl = 0; ctl < 4; ++ctl) {
            short8 bh = B8[((w * 4 + ctl) * 32 + ks * 4 + l4) * 16 + l15];
            acc[0][ctl] = __builtin_amdgcn_mfma_f32_16x16x32_bf16(ah0, bh, acc[0][ctl], 0, 0, 0);
            acc[1][ctl] = __builtin_amdgcn_mfma_f32_16x16x32_bf16(ah1, bh, acc[1][ctl], 0, 0, 0);
        }
    }

    // ---- Fold to per-row top-2; lane holds row rt*16+l4*4+r, code w*64+ctl*16+l15 ----
    float tb1[8], tb2[8];
    int ti1[8];
    #pragma unroll
    for (int s = 0; s < 8; ++s) { tb1[s] = 1e30f; tb2[s] = 1e30f; ti1[s] = 0x7fffffff; }
    #pragma unroll
    for (int ctl = 0; ctl < 4; ++ctl) {
        int k = w * 64 + ctl * 16 + l15;
        float e2v = e2s[k];
        #pragma unroll
        for (int rt = 0; rt < 2; ++rt)
            #pragma unroll
            for (int r = 0; r < 4; ++r) {
                int s = rt * 4 + r;
                float d = fmaf(-2.f, acc[rt][ctl][r], e2v);
                bool lt = d < tb1[s];  // k ascends with ctl: strict < keeps smallest k
                tb2[s] = lt ? tb1[s] : fminf(tb2[s], d);
                if (lt) { tb1[s] = d; ti1[s] = k; }
            }
    }
    #pragma unroll
    for (int s = 0; s < 8; ++s) {
        #pragma unroll
        for (int off = 1; off < 16; off <<= 1) {
            float ob1 = __shfl_xor(tb1[s], off, 16);
            int oi1 = __shfl_xor(ti1[s], off, 16);
            float ob2 = __shfl_xor(tb2[s], off, 16);
            bool take = (ob1 < tb1[s]) || (ob1 == tb1[s] && oi1 < ti1[s]);
            float loser = take ? tb1[s] : ob1;
            if (take) { tb1[s] = ob1; ti1[s] = oi1; }
            tb2[s] = fminf(fminf(tb2[s], ob2), loser);
        }
    }
    if (l15 == 0) {
        #pragma unroll
        for (int rt = 0; rt < 2; ++rt)
            #pragma unroll
            for (int r = 0; r < 4; ++r) {
                int row = rt * 16 + l4 * 4 + r;
                mb1[w][row] = tb1[rt * 4 + r];
                mb2[w][row] = tb2[rt * 4 + r];
                mi1[w][row] = ti1[rt * 4 + r];
            }
    }
    __syncthreads();

    // ---- Merge 16 waves; rigorous hi-only bound -> ambiguity limit ----
    if (tid < BRN) {
        float B1 = 1e30f, B2 = 1e30f;
        int I1 = 0x7fffffff;
        #pragma unroll
        for (int ww = 0; ww < NWAVE; ++ww) {
            float a1 = mb1[ww][tid], a2 = mb2[ww][tid];
            int ai = mi1[ww][tid];
            bool take = (a1 < B1) || (a1 == B1 && ai < I1);
            if (take) { B2 = fminf(B1, a2); B1 = a1; I1 = ai; }
            else      { B2 = fminf(B2, a1); }
        }
        besti[tid] = I1;
        float t2 = 2.f * (0.0079f * sqrtf(1.01f * x2s[tid] * e2mx) + 0.02f);
        lims[tid] = (B2 - B1 <= t2) ? (B1 + t2) : -1e30f;
    }
    __syncthreads();

    // ---- Pass A: parallel candidate collection from live acc registers ----
    #pragma unroll
    for (int rt = 0; rt < 2; ++rt)
        #pragma unroll
        for (int r = 0; r < 4; ++r) {
            int row = rt * 16 + l4 * 4 + r;
            float lim = lims[row];
            #pragma unroll
            for (int ctl = 0; ctl < 4; ++ctl) {
                int k = w * 64 + ctl * 16 + l15;
                float d = fmaf(-2.f, acc[rt][ctl][r], e2s[k]);
                if (d <= lim) {
                    int p = atomicAdd(&pair_cnt, 1);
                    if (p < PAIR_MAX) pairs[p] = (row << 10) | k;
                }
            }
        }
    __syncthreads();
    const int np = pair_cnt;

    if (np <= PAIR_MAX) {
        // ---- Pass B: one wave per pair, exact fp64 distance ----
        for (int pi = w; pi < np; pi += NWAVE) {
            int pr = pairs[pi];
            int row = pr >> 10, k = pr & 1023;
            float4 e4 = *(const float4*)&embed[(size_t)k * CDIM + 4 * l];
            double dot = 0.0;
            #pragma unroll
            for (int j = 0; j < 4; ++j)
                dot = fma((double)(&e4.x)[j],
                          (double)z_e[zbase + (size_t)(4 * l + j) * HW + row], dot);
            #pragma unroll
            for (int off = 1; off < 64; off <<= 1) dot += __shfl_xor(dot, off);
            if (l == 0) pd[pi] = e2d[k] - 2.0 * dot;
        }
        __syncthreads();
        // ---- Pass C: per-row exact min over candidates ----
        if (tid < BRN) {
            double fb = 1e300;
            int fi = 0x7fffffff;
            bool any = false;
            for (int p = 0; p < np; ++p)
                if ((pairs[p] >> 10) == tid) {
                    double d = pd[p];
                    int k = pairs[p] & 1023;
                    if (d < fb || (d == fb && k < fi)) { fb = d; fi = k; }
                    any = true;
                }
            if (any) besti[tid] = fi;
        }
    } else {
        // ---- Overflow fallback (ultra-rare): serial full fp64 per amb row ----
        for (int row = 0; row < BRN; ++row) {
            if (lims[row] < -9e29f) continue;  // uniform branch (LDS)
            if (tid < CDIM) xrow[tid] = z_e[zbase + (size_t)tid * HW + row];
            __syncthreads();
            int k = tid;  // 1024 threads = 1024 codes
            const float* er = embed + (size_t)k * CDIM;
            double dot = 0.0;
            for (int c = 0; c < CDIM; ++c)
                dot = fma((double)er[c], (double)xrow[c], dot);
            double bd = e2d[k] - 2.0 * dot;
            int bi = k;
            #pragma unroll
            for (int off = 1; off < 64; off <<= 1) {
                double od = __shfl_xor(bd, off);
                int oi = __shfl_xor(bi, off);
                if (od < bd || (od == bd && oi < bi)) { bd = od; bi = oi; }
            }
            if (l == 0) { red_d[w] = bd; red_i[w] = bi; }
            __syncthreads();
            if (tid == 0) {
                double fb = red_d[0];
                int fi = red_i[0];
                #pragma unroll
                for (int ww = 1; ww < NWAVE; ++ww)
                    if (red_d[ww] < fb || (red_d[ww] == fb && red_i[ww] < fi)) { fb = red_d[ww]; fi = red_i[ww]; }
                besti[row] = fi;
            }
            __syncthreads();
        }
    }
    __syncthreads();

    // ---- Fused epilogue: z_q_st, commitment-loss partial, idx, counts ----
    double lacc = 0.0;
    #pragma unroll
    for (int i = 0; i < 2; ++i) {
        int f4 = i * 1024 + tid;
        int c = f4 >> 3, r4 = (f4 & 7) << 2;
        float4 x4 = *(const float4*)&z_e[zbase + (size_t)c * HW + r4];
        float o4[4];
        #pragma unroll
        for (int j = 0; j < 4; ++j) {
            int k = besti[r4 + j];
            float q = embed[(size_t)k * CDIM + c];
            float x = (&x4.x)[j];
            float r = q - x;            // z_q - z_e in fp32 (reference rounding)
            o4[j] = x + r;              // straight-through value
            lacc = fma((double)r, (double)r, lacc);
        }
        *(float4*)&out_zq[zbase + (size_t)c * HW + r4] = make_float4(o4[0], o4[1], o4[2], o4[3]);
    }
    if (tid < BRN) {
        int k = besti[tid];
        out_idx[n0 + tid] = (float)k;
        atomicAdd(&counts[k], 1u);
    }
    #pragma unroll
    for (int off = 32; off; off >>= 1) lacc += __shfl_down(lacc, off);
    if (l == 0) red_d[w] = lacc;
    __syncthreads();
    if (tid == 0) {
        double t = 0.0;
        #pragma unroll
        for (int ww = 0; ww < NWAVE; ++ww) t += red_d[ww];
        atomicAdd(loss_sum, t);
    }
}

__global__ __launch_bounds__(256) void finalize_kernel(
        const unsigned* __restrict__ counts, const double* __restrict__ loss_sum,
        float* __restrict__ out) {
    int tid = threadIdx.x;
    float H = 0.f;
    for (int k = tid; k < KCODES; k += 256) {
        float p = (float)counts[k] / 32768.0f;
        H += p * logf(p + 1e-10f);
    }
    __shared__ float hr[4];
    #pragma unroll
    for (int off = 32; off; off >>= 1) H += __shfl_down(H, off);
    if ((tid & 63) == 0) hr[tid >> 6] = H;
    __syncthreads();
    if (tid == 0) {
        float Hs = hr[0] + hr[1] + hr[2] + hr[3];
        out[OUT_LOSS_OFF] = (float)(0.25 * (loss_sum[0] / (double)ZELEMS));
        out[OUT_PERP_OFF] = expf(-Hs);
    }
}

extern "C" void kernel_launch(void* const* d_in, const int* in_sizes, int n_in,
                              void* d_out, int out_size, void* d_ws, size_t ws_size,
                              hipStream_t stream) {
    const float* z_e = (const float*)d_in[0];
    const float* embed = (const float*)d_in[1];
    float* out = (float*)d_out;

    char* ws = (char*)d_ws;
    unsigned* ws_cnt = (unsigned*)(ws + WS_CNT_OFF);
    double* ws_e2d = (double*)(ws + WS_E2D_OFF);
    float* ws_e2f = (float*)(ws + WS_E2F_OFF);
    double* ws_loss = (double*)(ws + WS_LOSS_OFF);
    ushort* ws_bt = (ushort*)(ws + WS_BT_OFF);

    e2split_kernel<<<KCODES, 64, 0, stream>>>(embed, ws_e2d, ws_e2f, ws_bt, ws_cnt, ws_loss);
    argmin_fused_kernel<<<NROWS / BRN, 1024, 0, stream>>>(z_e, embed, ws_bt, ws_e2f, ws_e2d,
                                                          out + OUT_ZQ_OFF, out + OUT_IDX_OFF,
                                                          ws_cnt, ws_loss);
    finalize_kernel<<<1, 256, 0, stream>>>(ws_cnt, ws_loss, out);
}